// Round 8
// baseline (563.644 us; speedup 1.0000x reference)
//
#include <hip/hip_runtime.h>

typedef unsigned short u16;
typedef unsigned int u32;
typedef _Float16 f16;

using half8 = __attribute__((ext_vector_type(8))) _Float16;
using f32x4 = __attribute__((ext_vector_type(4))) float;
using f32x16 = __attribute__((ext_vector_type(16))) float;

// ---------------------------------------------------------------------------
// Prep 1: P1 = feats @ W1a (fp32, Qc folded later), P2h = f16(feats @ W1b)
// ---------------------------------------------------------------------------
__global__ __launch_bounds__(512) void prep_p12(const float* __restrict__ img,
                                                const float* __restrict__ gw1,
                                                float* __restrict__ P1,
                                                f16* __restrict__ P2h) {
    const int blk = blockIdx.x;
    const int n = blk >> 3;
    const int c0 = (blk & 7) * 8;
    const int t = threadIdx.x;
    __shared__ float feats[8][68];
    for (int idx = t; idx < 8 * 66; idx += 512) {
        int rr = idx / 66, cc = idx % 66, cell = c0 + rr;
        float v;
        if (cc < 64)       v = img[((size_t)(n * 64 + cc)) * 64 + cell];
        else if (cc == 64) v = (float)(cell >> 3);
        else               v = (float)(cell & 7);
        feats[rr][cc] = v;
    }
    __syncthreads();
    const int g = t;
    float a1[8], a2[8];
#pragma unroll
    for (int r = 0; r < 8; ++r) { a1[r] = 0.f; a2[r] = 0.f; }
    for (int c = 0; c < 66; ++c) {
        float wa = gw1[(size_t)c * 512 + g];
        float wb = gw1[(size_t)(66 + c) * 512 + g];
#pragma unroll
        for (int r = 0; r < 8; ++r) {
            a1[r] += feats[r][c] * wa;
            a2[r] += feats[r][c] * wb;
        }
    }
#pragma unroll
    for (int r = 0; r < 8; ++r) {
        P1[((size_t)(n * 64 + c0 + r)) * 512 + g] = a1[r];
        P2h[((size_t)(n * 64 + c0 + r)) * 512 + g] = (f16)a2[r];
    }
}

// ---------------------------------------------------------------------------
// Prep 2: Qc[n] = ques[n] @ W1c + b1; P1h = f16(P1 + Qc). Also zero Ctx.
// ---------------------------------------------------------------------------
__global__ __launch_bounds__(512) void prep_q2(const float* __restrict__ ques,
                                               const float* __restrict__ gw1,
                                               const float* __restrict__ gb1,
                                               const float* __restrict__ P1,
                                               f16* __restrict__ P1h,
                                               float* __restrict__ Ctx) {
    const int n = blockIdx.x;
    const int t = threadIdx.x;
    __shared__ float q[256];
    if (t < 256) q[t] = ques[(size_t)n * 256 + t];
    __syncthreads();
    float acc = gb1[t];
    for (int e = 0; e < 256; ++e)
        acc += q[e] * gw1[(size_t)(132 + e) * 512 + t];
    const float* src = P1 + (((size_t)(n * 64)) << 9) + t;
    f16* dst = P1h + (((size_t)(n * 64)) << 9) + t;
    for (int r = 0; r < 64; ++r)
        dst[(size_t)r * 512] = (f16)(src[(size_t)r * 512] + acc);
    Ctx[(size_t)n * 512 + t] = 0.f;
}

// ---------------------------------------------------------------------------
// Prep 3: reorder W2/W3/W4 (512x512 fp32 [k][n]) into K-chunk-major f16:
//   T'[ks][khalf][col][8]  (ks = k>>4, khalf = (k>>3)&1, j = k&7)
//   halfidx = ks*8192 + khalf*4096 + col*8 + j      (16 KB per ks chunk)
// Makes the fused kernel's per-wave B-fragment load CONTIGUOUS (512 B per
// half-wave, 8 cache lines vs the old 32-line gather).
// ---------------------------------------------------------------------------
__global__ void transpose_w(const float* __restrict__ W2, const float* __restrict__ W3,
                            const float* __restrict__ W4, f16* __restrict__ T2,
                            f16* __restrict__ T3, f16* __restrict__ T4) {
    const int L = blockIdx.z;
    const float* W = (L == 0) ? W2 : ((L == 1) ? W3 : W4);
    f16* T = (L == 0) ? T2 : ((L == 1) ? T3 : T4);
    __shared__ float tile[32][33];
    const int bx = blockIdx.x * 32;  // n origin
    const int by = blockIdx.y * 32;  // k origin
    const int tx = threadIdx.x, ty = threadIdx.y;
    for (int r = ty; r < 32; r += 8)
        tile[r][tx] = W[(size_t)(by + r) * 512 + bx + tx];
    __syncthreads();
    for (int r = ty; r < 32; r += 8) {
        const int n = bx + r, k = by + tx;
        T[(size_t)(k >> 4) * 8192 + ((k >> 3) & 1) * 4096 + n * 8 + (k & 7)] =
            (f16)tile[tx][r];
    }
}

// ---------------------------------------------------------------------------
// FUSED g-MLP layers 2..4 + mean-reduce. 32x32x16 MFMA, 1x8 N-split,
// H = 64 rows (ONE i-index per block) -> 64 KB LDS -> 2 BLOCKS/CU.
// Round-7 post-mortem: MFMA-busy was ~196us in BOTH round 6 (383us) and
// round 7 (427us) -- the math is at its floor; the difference is exposed
// stall. Root cause of the plateau: 128 KB LDS = 1 block/CU = 2 waves/SIMD
// (Occupancy 22%) -> construct/writeback barriers and K-loop latency idle
// the matrix pipe with nothing to fill it (54% idle). This version halves
// the block (H 64x512 = 64 KB) so TWO blocks co-reside (4 waves/SIMD):
// one block's serial phases overlap the other's MFMA phase.
// Register budget for 16 waves/CU (cap 128 total, m69): acc 64 AGPR
// (wave tile 64x64 = 2x2 f32x16) + B dbuf 16 + A transient 8 + addr ~25
// ~= 115-125. __launch_bounds__(512,4) pins the cap. Per-wave per ks:
// 2 coalesced B-loads (T', wv-disjoint) + 2 ds_read_b128 + 4 MFMA --
// same B L2 demand as round 6 (~19 TB/s agg, under the 34.5 roof).
// Fragment layouts (guide m74/m101):
//   A/B: row|col = lane&31, k = (lane>>5)*8 + j
//   C/D: col = lane&31, row = (reg&3) + 8*(reg>>2) + 4*(lane>>5)
// ---------------------------------------------------------------------------
__global__ __launch_bounds__(512, 4) void fused_g234(
    const f16* __restrict__ P1h, const f16* __restrict__ P2h,
    const f16* __restrict__ T2, const f16* __restrict__ T3,
    const f16* __restrict__ T4, const float* __restrict__ gb2,
    const float* __restrict__ gb3, const float* __restrict__ gb4,
    float* __restrict__ Ctx) {
    const int tid = threadIdx.x;
    const int lane = tid & 63;
    const int lane31 = lane & 31;
    const int khalf = lane >> 5;        // 0..1 (k-subgroup of 8 within ks*16)
    const int wv = tid >> 6;            // 0..7 (column group of 64)
    const int b = blockIdx.x;
    const int nb = b >> 6;              // image 0..63
    const int i0 = b & 63;              // the single i-index of this block

    __shared__ alignas(16) f16 H[64 * 512];    // 64 KB -> 2 blocks/CU

    const f16* P1b = P1h + (((size_t)(nb * 64 + i0)) << 9);
    const f16* P2b = P2h + (((size_t)(nb * 64)) << 9);

    // ---- construct layer-1 output: H[j] = relu(P1h[i0] + P2h[j]) ----
    // P1 fragment is row-invariant for the whole block: load once.
    {
        const int k0 = lane * 8;
        half8 x = *(const half8*)(P1b + k0);
#pragma unroll
        for (int u = 0; u < 8; ++u) {
            int r = u * 8 + wv;                     // r&7 == wv
            half8 y = *(const half8*)(P2b + (((size_t)r) << 9) + k0);
            half8 s = x + y;
            s = __builtin_elementwise_max(s, (half8)(f16)0.f);
            *(half8*)&H[r * 512 + (k0 ^ ((wv & 7) << 3))] = s;
        }
    }
    __syncthreads();

    f32x16 acc[2][2];
#pragma unroll
    for (int mi = 0; mi < 2; ++mi)
#pragma unroll
        for (int ni = 0; ni < 2; ++ni)
#pragma unroll
            for (int r = 0; r < 16; ++r)
                acc[mi][ni][r] = 0.f;

    const int swz = (lane31 & 7) << 3;  // A-row&7 == lane31&7 for both mi
    const int rbase0 = lane31 * 512;
    const int rbase1 = (32 + lane31) * 512;

    auto ldsA = [&](half8 (&a)[2], int ks) {
        const int koff = ((ks << 4) | (khalf << 3)) ^ swz;
        a[0] = *(const half8*)&H[rbase0 + koff];
        a[1] = *(const half8*)&H[rbase1 + koff];
    };
    // B fragment from T' chunk: contiguous 512B per half-wave (coalesced).
    auto ldB = [&](half8 (&bf)[2], const f16* __restrict__ T, int ks) {
        const f16* p = T + ks * 8192 + khalf * 4096 + (wv * 64 + lane31) * 8;
#pragma unroll
        for (int ni = 0; ni < 2; ++ni)
            bf[ni] = *(const half8*)(p + ni * 256);   // +32 cols
    };
    auto mfma4 = [&](half8 (&a)[2], half8 (&bf)[2]) {
        __builtin_amdgcn_s_setprio(1);
#pragma unroll
        for (int mi = 0; mi < 2; ++mi)
#pragma unroll
            for (int ni = 0; ni < 2; ++ni)
                acc[mi][ni] = __builtin_amdgcn_mfma_f32_32x32x16_f16(
                    a[mi], bf[ni], acc[mi][ni], 0, 0, 0);
        __builtin_amdgcn_s_setprio(0);
    };

    // One 512-K GEMM layer: 32 ks chunks (K=16) as 16 pairs. B double-
    // buffered with named bA/bB (static indexing); A read in-iteration.
    auto run_layer = [&](const f16* __restrict__ T) {
        half8 bA[2], bB[2];
        ldB(bA, T, 0);
        for (int k2 = 0; k2 < 16; ++k2) {
            const int ks = k2 * 2;
            ldB(bB, T, ks + 1);
            {
                half8 a[2];
                ldsA(a, ks);
                mfma4(a, bA);
            }
            if (k2 < 15) ldB(bA, T, ks + 2);
            {
                half8 a[2];
                ldsA(a, ks + 1);
                mfma4(a, bB);
            }
        }
    };

    // relu(acc+bias) -> f16 -> H (swizzled), zero acc. Two barriers.
    auto writeback = [&](const float* __restrict__ bias) {
        float bb[2];
#pragma unroll
        for (int ni = 0; ni < 2; ++ni)
            bb[ni] = bias[wv * 64 + ni * 32 + lane31];
        __syncthreads();                    // all waves done reading H
#pragma unroll
        for (int mi = 0; mi < 2; ++mi) {
#pragma unroll
            for (int ni = 0; ni < 2; ++ni) {
                const int col = wv * 64 + ni * 32 + lane31;
#pragma unroll
                for (int r = 0; r < 16; ++r) {
                    const int row = mi * 32 + (r & 3) + 4 * khalf + 8 * (r >> 2);
                    float v = fmaxf(acc[mi][ni][r] + bb[ni], 0.f);
                    H[row * 512 + (col ^ ((row & 7) << 3))] = (f16)v;
                    acc[mi][ni][r] = 0.f;
                }
            }
        }
        __syncthreads();                    // H rewrite complete
    };

    run_layer(T2);
    writeback(gb2);
    run_layer(T3);
    writeback(gb3);
    run_layer(T4);

    // ---- layer-4 epilogue: relu(acc+b4), col-sum over the block's 64 rows ----
#pragma unroll
    for (int ni = 0; ni < 2; ++ni) {
        const int col = wv * 64 + ni * 32 + lane31;
        float bb = gb4[col];
        float s = 0.f;
#pragma unroll
        for (int mi = 0; mi < 2; ++mi)
#pragma unroll
            for (int r = 0; r < 16; ++r)
                s += fmaxf(acc[mi][ni][r] + bb, 0.f);
        s += __shfl_xor(s, 32, 64);         // combine the two khalf lanes
        if (khalf == 0)
            atomicAdd(&Ctx[(((size_t)nb) << 9) + col], s);
    }
}

// ---------------------------------------------------------------------------
// f-MLP layer: Out[n, cs*64..+64) = relu(In[n,:]*scale @ W + b).
// ---------------------------------------------------------------------------
__global__ __launch_bounds__(512) void fmlp_layer(
    const float* __restrict__ In, const float* __restrict__ Wt,
    const float* __restrict__ bias, float* __restrict__ Out, float scale) {
    const int n = blockIdx.x, cs = blockIdx.y;
    const int t = threadIdx.x;
    const int col = cs * 64 + (t & 63);
    const int seg = t >> 6;
    __shared__ float a[512];
    __shared__ float red[512];
    a[t] = In[(size_t)n * 512 + t] * scale;
    __syncthreads();
    float p = 0.f;
#pragma unroll 8
    for (int i = seg * 64; i < seg * 64 + 64; ++i)
        p += a[i] * Wt[(size_t)i * 512 + col];
    red[t] = p;
    __syncthreads();
    if (t < 64) {
        float v = bias[col];
#pragma unroll
        for (int sg = 0; sg < 8; ++sg) v += red[sg * 64 + t];
        Out[(size_t)n * 512 + cs * 64 + t] = fmaxf(v, 0.f);
    }
}

// ---------------------------------------------------------------------------
// Final logits + log_softmax. grid 64, block 64 (one wave per batch row).
// ---------------------------------------------------------------------------
__global__ __launch_bounds__(64) void fmlp_out(
    const float* __restrict__ A2, const float* __restrict__ fw3,
    const float* __restrict__ fb3, float* __restrict__ out) {
    const int n = blockIdx.x;
    const int lane = threadIdx.x;
    float s0 = 0.f, s1 = 0.f;
    for (int i = lane; i < 512; i += 64) {
        float v = A2[(size_t)n * 512 + i];
        s0 += v * fw3[i * 2];
        s1 += v * fw3[i * 2 + 1];
    }
#pragma unroll
    for (int d = 1; d < 64; d <<= 1) {
        s0 += __shfl_xor(s0, d, 64);
        s1 += __shfl_xor(s1, d, 64);
    }
    if (lane == 0) {
        s0 += fb3[0];
        s1 += fb3[1];
        float m = fmaxf(s0, s1);
        float l = logf(expf(s0 - m) + expf(s1 - m)) + m;
        out[n * 2 + 0] = s0 - l;
        out[n * 2 + 1] = s1 - l;
    }
}

// ---------------------------------------------------------------------------
extern "C" void kernel_launch(void* const* d_in, const int* in_sizes, int n_in,
                              void* d_out, int out_size, void* d_ws, size_t ws_size,
                              hipStream_t stream) {
    const float* img  = (const float*)d_in[0];
    const float* ques = (const float*)d_in[1];
    const float* gw1  = (const float*)d_in[2];
    const float* gb1  = (const float*)d_in[3];
    const float* gw2  = (const float*)d_in[4];
    const float* gb2  = (const float*)d_in[5];
    const float* gw3  = (const float*)d_in[6];
    const float* gb3  = (const float*)d_in[7];
    const float* gw4  = (const float*)d_in[8];
    const float* gb4  = (const float*)d_in[9];
    const float* fw1  = (const float*)d_in[10];
    const float* fb1  = (const float*)d_in[11];
    const float* fw2  = (const float*)d_in[12];
    const float* fb2  = (const float*)d_in[13];
    const float* fw3  = (const float*)d_in[14];
    const float* fb3  = (const float*)d_in[15];

    char* ws = (char*)d_ws;
    size_t off = 0;
    float* P1  = (float*)(ws + off); off += (size_t)4096 * 512 * 4;   // 8 MB fp32 scratch
    f16* P1h = (f16*)(ws + off); off += (size_t)4096 * 512 * 2;       // 4 MB (P1+Qc, f16)
    f16* P2h = (f16*)(ws + off); off += (size_t)4096 * 512 * 2;       // 4 MB
    float* Ctx = (float*)(ws + off); off += (size_t)64 * 512 * 4;
    float* Z1  = (float*)(ws + off); off += (size_t)64 * 512 * 4;
    float* Z2  = (float*)(ws + off); off += (size_t)64 * 512 * 4;
    f16* T2 = (f16*)(ws + off); off += (size_t)512 * 512 * 2;
    f16* T3 = (f16*)(ws + off); off += (size_t)512 * 512 * 2;
    f16* T4 = (f16*)(ws + off); off += (size_t)512 * 512 * 2;

    prep_p12<<<512, 512, 0, stream>>>(img, gw1, P1, P2h);
    prep_q2<<<64, 512, 0, stream>>>(ques, gw1, gb1, P1, P1h, Ctx);
    transpose_w<<<dim3(16, 16, 3), dim3(32, 8), 0, stream>>>(gw2, gw3, gw4, T2, T3, T4);

    // one fused dispatch; 64-row blocks, 2 co-resident per CU
    fused_g234<<<4096, 512, 0, stream>>>(P1h, P2h, T2, T3, T4, gb2, gb3, gb4, Ctx);

    fmlp_layer<<<dim3(64, 8), 512, 0, stream>>>(Ctx, fw1, fb1, Z1, 1.0f / 4096.0f);
    fmlp_layer<<<dim3(64, 8), 512, 0, stream>>>(Z1, fw2, fb2, Z2, 1.0f);
    fmlp_out<<<64, 64, 0, stream>>>(Z2, fw3, fb3, (float*)d_out);
}

// Round 9
// 559.334 us; speedup vs baseline: 1.0077x; 1.0077x over previous
//
#include <hip/hip_runtime.h>

typedef unsigned short u16;
typedef unsigned int u32;
typedef _Float16 f16;

using half8 = __attribute__((ext_vector_type(8))) _Float16;
using f32x4 = __attribute__((ext_vector_type(4))) float;
using f32x16 = __attribute__((ext_vector_type(16))) float;

// Chunk-major activation layout (MFMA-fragment-native), per image n:
//   idx(n,k,cell) = n*32768 + (k>>4)*1024 + ((k>>3)&1)*512 + cell*8 + (k&7)
// i.e. [ks:32][khalf:2][cell:64][j:8]. A wave reading all 64 cells' 16B
// fragments at fixed (ks,khalf) touches contiguous memory.

// ---------------------------------------------------------------------------
// Prep 1: P1 = feats @ W1a (fp32 row-major, Qc folded later),
//         P2c = f16(feats @ W1b) in chunk-major layout.
// ---------------------------------------------------------------------------
__global__ __launch_bounds__(512) void prep_p12(const float* __restrict__ img,
                                                const float* __restrict__ gw1,
                                                float* __restrict__ P1,
                                                f16* __restrict__ P2c) {
    const int blk = blockIdx.x;
    const int n = blk >> 3;
    const int c0 = (blk & 7) * 8;
    const int t = threadIdx.x;
    __shared__ float feats[8][68];
    for (int idx = t; idx < 8 * 66; idx += 512) {
        int rr = idx / 66, cc = idx % 66, cell = c0 + rr;
        float v;
        if (cc < 64)       v = img[((size_t)(n * 64 + cc)) * 64 + cell];
        else if (cc == 64) v = (float)(cell >> 3);
        else               v = (float)(cell & 7);
        feats[rr][cc] = v;
    }
    __syncthreads();
    const int g = t;
    float a1[8], a2[8];
#pragma unroll
    for (int r = 0; r < 8; ++r) { a1[r] = 0.f; a2[r] = 0.f; }
    for (int c = 0; c < 66; ++c) {
        float wa = gw1[(size_t)c * 512 + g];
        float wb = gw1[(size_t)(66 + c) * 512 + g];
#pragma unroll
        for (int r = 0; r < 8; ++r) {
            a1[r] += feats[r][c] * wa;
            a2[r] += feats[r][c] * wb;
        }
    }
    const size_t cb = (size_t)n * 32768 + (g >> 4) * 1024 + ((g >> 3) & 1) * 512 + (g & 7);
#pragma unroll
    for (int r = 0; r < 8; ++r) {
        P1[((size_t)(n * 64 + c0 + r)) * 512 + g] = a1[r];
        P2c[cb + (c0 + r) * 8] = (f16)a2[r];
    }
}

// ---------------------------------------------------------------------------
// Prep 2: Qc[n] = ques[n] @ W1c + b1; P1c = f16(P1 + Qc) chunk-major. Zero Ctx.
// ---------------------------------------------------------------------------
__global__ __launch_bounds__(512) void prep_q2(const float* __restrict__ ques,
                                               const float* __restrict__ gw1,
                                               const float* __restrict__ gb1,
                                               const float* __restrict__ P1,
                                               f16* __restrict__ P1c,
                                               float* __restrict__ Ctx) {
    const int n = blockIdx.x;
    const int t = threadIdx.x;
    __shared__ float q[256];
    if (t < 256) q[t] = ques[(size_t)n * 256 + t];
    __syncthreads();
    float acc = gb1[t];
    for (int e = 0; e < 256; ++e)
        acc += q[e] * gw1[(size_t)(132 + e) * 512 + t];
    const float* src = P1 + (((size_t)(n * 64)) << 9) + t;
    const size_t cb = (size_t)n * 32768 + (t >> 4) * 1024 + ((t >> 3) & 1) * 512 + (t & 7);
    for (int r = 0; r < 64; ++r)
        P1c[cb + r * 8] = (f16)(src[(size_t)r * 512] + acc);
    Ctx[(size_t)n * 512 + t] = 0.f;
}

// ---------------------------------------------------------------------------
// Prep 3: reorder W2/W3/W4 (512x512 fp32 [k][n]) into K-chunk-major f16:
//   T'[ks][khalf][col][8]: halfidx = ks*8192 + khalf*4096 + col*8 + (k&7)
// (16 KB per ks chunk; per-wave B-fragment loads are contiguous 512 B.)
// ---------------------------------------------------------------------------
__global__ void transpose_w(const float* __restrict__ W2, const float* __restrict__ W3,
                            const float* __restrict__ W4, f16* __restrict__ T2,
                            f16* __restrict__ T3, f16* __restrict__ T4) {
    const int L = blockIdx.z;
    const float* W = (L == 0) ? W2 : ((L == 1) ? W3 : W4);
    f16* T = (L == 0) ? T2 : ((L == 1) ? T3 : T4);
    __shared__ float tile[32][33];
    const int bx = blockIdx.x * 32;  // n origin
    const int by = blockIdx.y * 32;  // k origin
    const int tx = threadIdx.x, ty = threadIdx.y;
    for (int r = ty; r < 32; r += 8)
        tile[r][tx] = W[(size_t)(by + r) * 512 + bx + tx];
    __syncthreads();
    for (int r = ty; r < 32; r += 8) {
        const int n = bx + r, k = by + tx;
        T[(size_t)(k >> 4) * 8192 + ((k >> 3) & 1) * 4096 + n * 8 + (k & 7)] =
            (f16)tile[tx][r];
    }
}

// ---------------------------------------------------------------------------
// FUSED g-MLP layers 2..4 + mean-reduce. 32x32x16 MFMA, 1x8 N-split,
// H = 64 rows (one i-index/block), 64 KB LDS, (512,4) -> 2 blocks/CU.
// Round-8 post-mortem: 4 waves/SIMD kept MFMA-busy at ~193us through the
// serial phases (despite spilling!), but arch demand ~110 > the 64-reg cap
// -> 385 MB scratch. This version fits the cap:
//  - H in chunk-major [ks][khalf][slot][8] with slot = row ^ f,
//    f = ((ks&1)<<1)|khalf. K-loop A-reads: contiguous-permuted 512B per
//    half-wave -> ZERO bank conflicts (was 4-way, 2.5e7 cyc). Construct:
//    1KB-contiguous LDS writes from coalesced P1c/P2c chunk reads.
//  - K-loop regs = round-6-proven minimum: B depth-1 prefetch (bfn 8),
//    A transient (8); arch live ~50 < 64. acc[2][2] = 64 AGPR.
//  - Writeback slot XOR spreads the 4 col-groups across 4 distinct 16B
//    windows (16-bank spread, same as the proven round-6 writeback).
// Fragment layouts (guide m74/m101):
//   A/B: row|col = lane&31, k = (lane>>5)*8 + j
//   C/D: col = lane&31, row = (reg&3) + 8*(reg>>2) + 4*(lane>>5)
// ---------------------------------------------------------------------------
__global__ __launch_bounds__(512, 4) void fused_g234(
    const f16* __restrict__ P1c, const f16* __restrict__ P2c,
    const f16* __restrict__ T2, const f16* __restrict__ T3,
    const f16* __restrict__ T4, const float* __restrict__ gb2,
    const float* __restrict__ gb3, const float* __restrict__ gb4,
    float* __restrict__ Ctx) {
    const int tid = threadIdx.x;
    const int lane = tid & 63;
    const int lane31 = lane & 31;
    const int khalf = lane >> 5;        // 0..1 (k-subgroup of 8 within ks*16)
    const int wv = tid >> 6;            // 0..7 (column group of 64)
    const int b = blockIdx.x;
    const int nb = b >> 6;              // image 0..63
    const int i0 = b & 63;              // the single i-index of this block

    __shared__ alignas(16) f16 H[64 * 1024];   // 64 KB, [ks][khalf][slot][8]

    const f16* P1b = P1c + (size_t)nb * 32768;
    const f16* P2b = P2c + (size_t)nb * 32768;

    // ---- construct: H[r][k] = relu(P1[i0][k] + P2[r][k]), chunk-major ----
    // wave wv owns ks = wv*4+u. Per iter: coalesced 512B reads, 1KB LDS write.
#pragma unroll
    for (int u = 0; u < 4; ++u) {
        const int ks = wv * 4 + u;
        const int cb = ks * 1024 + khalf * 512;
        const int f = ((ks & 1) << 1) | khalf;
        half8 x = *(const half8*)(P1b + cb + i0 * 8);
#pragma unroll
        for (int rr = 0; rr < 2; ++rr) {
            half8 y = *(const half8*)(P2b + cb + (rr * 32 + lane31) * 8);
            half8 s = x + y;
            s = __builtin_elementwise_max(s, (half8)(f16)0.f);
            *(half8*)&H[cb + (rr * 32 + (lane31 ^ f)) * 8] = s;
        }
    }
    __syncthreads();

    f32x16 acc[2][2];
#pragma unroll
    for (int mi = 0; mi < 2; ++mi)
#pragma unroll
        for (int ni = 0; ni < 2; ++ni)
#pragma unroll
            for (int r = 0; r < 16; ++r)
                acc[mi][ni][r] = 0.f;

    auto ldsA = [&](half8 (&a)[2], int ks) {
        const int f = ((ks & 1) << 1) | khalf;
        const int base = ks * 1024 + khalf * 512 + (lane31 ^ f) * 8;
        a[0] = *(const half8*)&H[base];
        a[1] = *(const half8*)&H[base + 256];     // +32 slots
    };
    // B fragment from T' chunk: contiguous 512B per half-wave (coalesced).
    auto ldB = [&](half8 (&bf)[2], const f16* __restrict__ T, int ks) {
        const f16* p = T + ks * 8192 + khalf * 4096 + (wv * 64 + lane31) * 8;
#pragma unroll
        for (int ni = 0; ni < 2; ++ni)
            bf[ni] = *(const half8*)(p + ni * 256);   // +32 cols
    };
    auto mfma4 = [&](half8 (&a)[2], half8 (&bf)[2]) {
        __builtin_amdgcn_s_setprio(1);
#pragma unroll
        for (int mi = 0; mi < 2; ++mi)
#pragma unroll
            for (int ni = 0; ni < 2; ++ni)
                acc[mi][ni] = __builtin_amdgcn_mfma_f32_32x32x16_f16(
                    a[mi], bf[ni], acc[mi][ni], 0, 0, 0);
        __builtin_amdgcn_s_setprio(0);
    };

    // One 512-K layer: 32 ks chunks. B prefetched depth-1; A in-iteration.
    auto run_layer = [&](const f16* __restrict__ T) {
        half8 bfn[2];
        ldB(bfn, T, 0);
#pragma unroll 2
        for (int ks = 0; ks < 32; ++ks) {
            half8 bf[2] = {bfn[0], bfn[1]};
            if (ks < 31) ldB(bfn, T, ks + 1);
            half8 a[2];
            ldsA(a, ks);
            mfma4(a, bf);
        }
    };

    // relu(acc+bias) -> f16 -> H chunk-major (slot XOR). Two barriers.
    auto writeback = [&](const float* __restrict__ bias) {
        float bb[2];
#pragma unroll
        for (int ni = 0; ni < 2; ++ni)
            bb[ni] = bias[wv * 64 + ni * 32 + lane31];
        __syncthreads();                    // all waves done reading H
#pragma unroll
        for (int ni = 0; ni < 2; ++ni) {
            const int c = wv * 64 + ni * 32 + lane31;
            const int cbase = (c >> 4) * 1024 + ((c >> 3) & 1) * 512;
            const int fw = (((c >> 4) & 1) << 1) | ((c >> 3) & 1);
            const int j = c & 7;
#pragma unroll
            for (int mi = 0; mi < 2; ++mi) {
#pragma unroll
                for (int r = 0; r < 16; ++r) {
                    const int row = mi * 32 + (r & 3) + 4 * khalf + 8 * (r >> 2);
                    float v = fmaxf(acc[mi][ni][r] + bb[ni], 0.f);
                    H[cbase + (row ^ fw) * 8 + j] = (f16)v;
                    acc[mi][ni][r] = 0.f;
                }
            }
        }
        __syncthreads();                    // H rewrite complete
    };

    run_layer(T2);
    writeback(gb2);
    run_layer(T3);
    writeback(gb3);
    run_layer(T4);

    // ---- layer-4 epilogue: relu(acc+b4), col-sum over the block's 64 rows ----
#pragma unroll
    for (int ni = 0; ni < 2; ++ni) {
        const int col = wv * 64 + ni * 32 + lane31;
        float bb = gb4[col];
        float s = 0.f;
#pragma unroll
        for (int mi = 0; mi < 2; ++mi)
#pragma unroll
            for (int r = 0; r < 16; ++r)
                s += fmaxf(acc[mi][ni][r] + bb, 0.f);
        s += __shfl_xor(s, 32, 64);         // combine the two khalf lanes
        if (khalf == 0)
            atomicAdd(&Ctx[(((size_t)nb) << 9) + col], s);
    }
}

// ---------------------------------------------------------------------------
// f-MLP layer: Out[n, cs*64..+64) = relu(In[n,:]*scale @ W + b).
// ---------------------------------------------------------------------------
__global__ __launch_bounds__(512) void fmlp_layer(
    const float* __restrict__ In, const float* __restrict__ Wt,
    const float* __restrict__ bias, float* __restrict__ Out, float scale) {
    const int n = blockIdx.x, cs = blockIdx.y;
    const int t = threadIdx.x;
    const int col = cs * 64 + (t & 63);
    const int seg = t >> 6;
    __shared__ float a[512];
    __shared__ float red[512];
    a[t] = In[(size_t)n * 512 + t] * scale;
    __syncthreads();
    float p = 0.f;
#pragma unroll 8
    for (int i = seg * 64; i < seg * 64 + 64; ++i)
        p += a[i] * Wt[(size_t)i * 512 + col];
    red[t] = p;
    __syncthreads();
    if (t < 64) {
        float v = bias[col];
#pragma unroll
        for (int sg = 0; sg < 8; ++sg) v += red[sg * 64 + t];
        Out[(size_t)n * 512 + cs * 64 + t] = fmaxf(v, 0.f);
    }
}

// ---------------------------------------------------------------------------
// Final logits + log_softmax. grid 64, block 64 (one wave per batch row).
// ---------------------------------------------------------------------------
__global__ __launch_bounds__(64) void fmlp_out(
    const float* __restrict__ A2, const float* __restrict__ fw3,
    const float* __restrict__ fb3, float* __restrict__ out) {
    const int n = blockIdx.x;
    const int lane = threadIdx.x;
    float s0 = 0.f, s1 = 0.f;
    for (int i = lane; i < 512; i += 64) {
        float v = A2[(size_t)n * 512 + i];
        s0 += v * fw3[i * 2];
        s1 += v * fw3[i * 2 + 1];
    }
#pragma unroll
    for (int d = 1; d < 64; d <<= 1) {
        s0 += __shfl_xor(s0, d, 64);
        s1 += __shfl_xor(s1, d, 64);
    }
    if (lane == 0) {
        s0 += fb3[0];
        s1 += fb3[1];
        float m = fmaxf(s0, s1);
        float l = logf(expf(s0 - m) + expf(s1 - m)) + m;
        out[n * 2 + 0] = s0 - l;
        out[n * 2 + 1] = s1 - l;
    }
}

// ---------------------------------------------------------------------------
extern "C" void kernel_launch(void* const* d_in, const int* in_sizes, int n_in,
                              void* d_out, int out_size, void* d_ws, size_t ws_size,
                              hipStream_t stream) {
    const float* img  = (const float*)d_in[0];
    const float* ques = (const float*)d_in[1];
    const float* gw1  = (const float*)d_in[2];
    const float* gb1  = (const float*)d_in[3];
    const float* gw2  = (const float*)d_in[4];
    const float* gb2  = (const float*)d_in[5];
    const float* gw3  = (const float*)d_in[6];
    const float* gb3  = (const float*)d_in[7];
    const float* gw4  = (const float*)d_in[8];
    const float* gb4  = (const float*)d_in[9];
    const float* fw1  = (const float*)d_in[10];
    const float* fb1  = (const float*)d_in[11];
    const float* fw2  = (const float*)d_in[12];
    const float* fb2  = (const float*)d_in[13];
    const float* fw3  = (const float*)d_in[14];
    const float* fb3  = (const float*)d_in[15];

    char* ws = (char*)d_ws;
    size_t off = 0;
    float* P1  = (float*)(ws + off); off += (size_t)4096 * 512 * 4;   // 8 MB fp32 scratch
    f16* P1c = (f16*)(ws + off); off += (size_t)4096 * 512 * 2;       // 4 MB chunk-major
    f16* P2c = (f16*)(ws + off); off += (size_t)4096 * 512 * 2;       // 4 MB chunk-major
    float* Ctx = (float*)(ws + off); off += (size_t)64 * 512 * 4;
    float* Z1  = (float*)(ws + off); off += (size_t)64 * 512 * 4;
    float* Z2  = (float*)(ws + off); off += (size_t)64 * 512 * 4;
    f16* T2 = (f16*)(ws + off); off += (size_t)512 * 512 * 2;
    f16* T3 = (f16*)(ws + off); off += (size_t)512 * 512 * 2;
    f16* T4 = (f16*)(ws + off); off += (size_t)512 * 512 * 2;

    prep_p12<<<512, 512, 0, stream>>>(img, gw1, P1, P2c);
    prep_q2<<<64, 512, 0, stream>>>(ques, gw1, gb1, P1, P1c, Ctx);
    transpose_w<<<dim3(16, 16, 3), dim3(32, 8), 0, stream>>>(gw2, gw3, gw4, T2, T3, T4);

    // one fused dispatch; 64-row blocks, 2 co-resident per CU
    fused_g234<<<4096, 512, 0, stream>>>(P1c, P2c, T2, T3, T4, gb2, gb3, gb4, Ctx);

    fmlp_layer<<<dim3(64, 8), 512, 0, stream>>>(Ctx, fw1, fb1, Z1, 1.0f / 4096.0f);
    fmlp_layer<<<dim3(64, 8), 512, 0, stream>>>(Z1, fw2, fb2, Z2, 1.0f);
    fmlp_out<<<64, 64, 0, stream>>>(Z2, fw3, fb3, (float*)d_out);
}

// Round 10
// 543.850 us; speedup vs baseline: 1.0364x; 1.0285x over previous
//
#include <hip/hip_runtime.h>

typedef unsigned short u16;
typedef unsigned int u32;
typedef _Float16 f16;

using half8 = __attribute__((ext_vector_type(8))) _Float16;
using f32x4 = __attribute__((ext_vector_type(4))) float;
using f32x16 = __attribute__((ext_vector_type(16))) float;

// Chunk-major activation layout (MFMA-fragment-native), per image n:
//   idx(n,k,cell) = n*32768 + (k>>4)*1024 + ((k>>3)&1)*512 + cell*8 + (k&7)
// i.e. [ks:32][khalf:2][cell:64][j:8]. A wave reading all 64 cells' 16B
// fragments at fixed (ks,khalf) touches contiguous memory.

// ---------------------------------------------------------------------------
// Prep 1: P1 = feats @ W1a (fp32 row-major, Qc folded later),
//         P2c = f16(feats @ W1b) in chunk-major layout.
// ---------------------------------------------------------------------------
__global__ __launch_bounds__(512) void prep_p12(const float* __restrict__ img,
                                                const float* __restrict__ gw1,
                                                float* __restrict__ P1,
                                                f16* __restrict__ P2c) {
    const int blk = blockIdx.x;
    const int n = blk >> 3;
    const int c0 = (blk & 7) * 8;
    const int t = threadIdx.x;
    __shared__ float feats[8][68];
    for (int idx = t; idx < 8 * 66; idx += 512) {
        int rr = idx / 66, cc = idx % 66, cell = c0 + rr;
        float v;
        if (cc < 64)       v = img[((size_t)(n * 64 + cc)) * 64 + cell];
        else if (cc == 64) v = (float)(cell >> 3);
        else               v = (float)(cell & 7);
        feats[rr][cc] = v;
    }
    __syncthreads();
    const int g = t;
    float a1[8], a2[8];
#pragma unroll
    for (int r = 0; r < 8; ++r) { a1[r] = 0.f; a2[r] = 0.f; }
    for (int c = 0; c < 66; ++c) {
        float wa = gw1[(size_t)c * 512 + g];
        float wb = gw1[(size_t)(66 + c) * 512 + g];
#pragma unroll
        for (int r = 0; r < 8; ++r) {
            a1[r] += feats[r][c] * wa;
            a2[r] += feats[r][c] * wb;
        }
    }
    const size_t cb = (size_t)n * 32768 + (g >> 4) * 1024 + ((g >> 3) & 1) * 512 + (g & 7);
#pragma unroll
    for (int r = 0; r < 8; ++r) {
        P1[((size_t)(n * 64 + c0 + r)) * 512 + g] = a1[r];
        P2c[cb + (c0 + r) * 8] = (f16)a2[r];
    }
}

// ---------------------------------------------------------------------------
// Prep 2: Qc[n] = ques[n] @ W1c + b1; P1c = f16(P1 + Qc) chunk-major. Zero Ctx.
// ---------------------------------------------------------------------------
__global__ __launch_bounds__(512) void prep_q2(const float* __restrict__ ques,
                                               const float* __restrict__ gw1,
                                               const float* __restrict__ gb1,
                                               const float* __restrict__ P1,
                                               f16* __restrict__ P1c,
                                               float* __restrict__ Ctx) {
    const int n = blockIdx.x;
    const int t = threadIdx.x;
    __shared__ float q[256];
    if (t < 256) q[t] = ques[(size_t)n * 256 + t];
    __syncthreads();
    float acc = gb1[t];
    for (int e = 0; e < 256; ++e)
        acc += q[e] * gw1[(size_t)(132 + e) * 512 + t];
    const float* src = P1 + (((size_t)(n * 64)) << 9) + t;
    const size_t cb = (size_t)n * 32768 + (t >> 4) * 1024 + ((t >> 3) & 1) * 512 + (t & 7);
    for (int r = 0; r < 64; ++r)
        P1c[cb + r * 8] = (f16)(src[(size_t)r * 512] + acc);
    Ctx[(size_t)n * 512 + t] = 0.f;
}

// ---------------------------------------------------------------------------
// Prep 3: reorder W2/W3/W4 (512x512 fp32 [k][n]) into K-chunk-major f16:
//   T'[ks][khalf][col][8]: halfidx = ks*8192 + khalf*4096 + col*8 + (k&7)
// (16 KB per ks chunk; per-wave B-fragment loads are contiguous 512 B.)
// ---------------------------------------------------------------------------
__global__ void transpose_w(const float* __restrict__ W2, const float* __restrict__ W3,
                            const float* __restrict__ W4, f16* __restrict__ T2,
                            f16* __restrict__ T3, f16* __restrict__ T4) {
    const int L = blockIdx.z;
    const float* W = (L == 0) ? W2 : ((L == 1) ? W3 : W4);
    f16* T = (L == 0) ? T2 : ((L == 1) ? T3 : T4);
    __shared__ float tile[32][33];
    const int bx = blockIdx.x * 32;  // n origin
    const int by = blockIdx.y * 32;  // k origin
    const int tx = threadIdx.x, ty = threadIdx.y;
    for (int r = ty; r < 32; r += 8)
        tile[r][tx] = W[(size_t)(by + r) * 512 + bx + tx];
    __syncthreads();
    for (int r = ty; r < 32; r += 8) {
        const int n = bx + r, k = by + tx;
        T[(size_t)(k >> 4) * 8192 + ((k >> 3) & 1) * 4096 + n * 8 + (k & 7)] =
            (f16)tile[tx][r];
    }
}

// ---------------------------------------------------------------------------
// FUSED g-MLP layers 2..4 + mean-reduce. 32x32x16 MFMA, 1x8 N-split,
// H = 64 rows (one i-index/block), 64 KB LDS, (512,4) -> 2 blocks/CU.
// Round-9 post-mortem: chunk-major H delivered ZERO bank conflicts and no
// spill (VGPR 88), but H was declared [64*1024] f16 = 128 KB while the
// index space is only [32][2][64][8] = 32768 f16 = 64 KB -- the oversized
// declaration kept LDS_Block_Size at 131072 -> 1 block/CU -> occupancy
// stuck at 22% and MfmaUtil at 42%. THE fix: H[32*1024] (64 KB) -> 2
// blocks/CU, 4 waves/SIMD -> one block's construct/writeback/K-loop gaps
// overlap the other's MFMA phase (r8 proved occupancy feeds the pipe).
//  - H chunk-major [ks][khalf][slot][8], slot = row ^ f, f=((ks&1)<<1)|khalf:
//    K-loop A-reads contiguous-permuted 512B/half-wave, 0 conflicts.
//  - K-loop regs: B depth-1 prefetch (8) + A transient (8); VGPR 88 < 128.
//  - Writeback slot XOR spreads 4 col-groups over 4 16B windows.
// Fragment layouts (guide m74/m101):
//   A/B: row|col = lane&31, k = (lane>>5)*8 + j
//   C/D: col = lane&31, row = (reg&3) + 8*(reg>>2) + 4*(lane>>5)
// ---------------------------------------------------------------------------
__global__ __launch_bounds__(512, 4) void fused_g234(
    const f16* __restrict__ P1c, const f16* __restrict__ P2c,
    const f16* __restrict__ T2, const f16* __restrict__ T3,
    const f16* __restrict__ T4, const float* __restrict__ gb2,
    const float* __restrict__ gb3, const float* __restrict__ gb4,
    float* __restrict__ Ctx) {
    const int tid = threadIdx.x;
    const int lane = tid & 63;
    const int lane31 = lane & 31;
    const int khalf = lane >> 5;        // 0..1 (k-subgroup of 8 within ks*16)
    const int wv = tid >> 6;            // 0..7 (column group of 64)
    const int b = blockIdx.x;
    const int nb = b >> 6;              // image 0..63
    const int i0 = b & 63;              // the single i-index of this block

    __shared__ alignas(16) f16 H[32 * 1024];   // 64 KB exactly -> 2 blocks/CU

    const f16* P1b = P1c + (size_t)nb * 32768;
    const f16* P2b = P2c + (size_t)nb * 32768;

    // ---- construct: H[r][k] = relu(P1[i0][k] + P2[r][k]), chunk-major ----
    // wave wv owns ks = wv*4+u. Per iter: coalesced 512B reads, 1KB LDS write.
#pragma unroll
    for (int u = 0; u < 4; ++u) {
        const int ks = wv * 4 + u;
        const int cb = ks * 1024 + khalf * 512;
        const int f = ((ks & 1) << 1) | khalf;
        half8 x = *(const half8*)(P1b + cb + i0 * 8);
#pragma unroll
        for (int rr = 0; rr < 2; ++rr) {
            half8 y = *(const half8*)(P2b + cb + (rr * 32 + lane31) * 8);
            half8 s = x + y;
            s = __builtin_elementwise_max(s, (half8)(f16)0.f);
            *(half8*)&H[cb + (rr * 32 + (lane31 ^ f)) * 8] = s;
        }
    }
    __syncthreads();

    f32x16 acc[2][2];
#pragma unroll
    for (int mi = 0; mi < 2; ++mi)
#pragma unroll
        for (int ni = 0; ni < 2; ++ni)
#pragma unroll
            for (int r = 0; r < 16; ++r)
                acc[mi][ni][r] = 0.f;

    auto ldsA = [&](half8 (&a)[2], int ks) {
        const int f = ((ks & 1) << 1) | khalf;
        const int base = ks * 1024 + khalf * 512 + (lane31 ^ f) * 8;
        a[0] = *(const half8*)&H[base];
        a[1] = *(const half8*)&H[base + 256];     // +32 slots
    };
    // B fragment from T' chunk: contiguous 512B per half-wave (coalesced).
    auto ldB = [&](half8 (&bf)[2], const f16* __restrict__ T, int ks) {
        const f16* p = T + ks * 8192 + khalf * 4096 + (wv * 64 + lane31) * 8;
#pragma unroll
        for (int ni = 0; ni < 2; ++ni)
            bf[ni] = *(const half8*)(p + ni * 256);   // +32 cols
    };
    auto mfma4 = [&](half8 (&a)[2], half8 (&bf)[2]) {
        __builtin_amdgcn_s_setprio(1);
#pragma unroll
        for (int mi = 0; mi < 2; ++mi)
#pragma unroll
            for (int ni = 0; ni < 2; ++ni)
                acc[mi][ni] = __builtin_amdgcn_mfma_f32_32x32x16_f16(
                    a[mi], bf[ni], acc[mi][ni], 0, 0, 0);
        __builtin_amdgcn_s_setprio(0);
    };

    // One 512-K layer: 32 ks chunks. B prefetched depth-1; A in-iteration.
    auto run_layer = [&](const f16* __restrict__ T) {
        half8 bfn[2];
        ldB(bfn, T, 0);
#pragma unroll 2
        for (int ks = 0; ks < 32; ++ks) {
            half8 bf[2] = {bfn[0], bfn[1]};
            if (ks < 31) ldB(bfn, T, ks + 1);
            half8 a[2];
            ldsA(a, ks);
            mfma4(a, bf);
        }
    };

    // relu(acc+bias) -> f16 -> H chunk-major (slot XOR). Two barriers.
    auto writeback = [&](const float* __restrict__ bias) {
        float bb[2];
#pragma unroll
        for (int ni = 0; ni < 2; ++ni)
            bb[ni] = bias[wv * 64 + ni * 32 + lane31];
        __syncthreads();                    // all waves done reading H
#pragma unroll
        for (int ni = 0; ni < 2; ++ni) {
            const int c = wv * 64 + ni * 32 + lane31;
            const int cbase = (c >> 4) * 1024 + ((c >> 3) & 1) * 512;
            const int fw = (((c >> 4) & 1) << 1) | ((c >> 3) & 1);
            const int j = c & 7;
#pragma unroll
            for (int mi = 0; mi < 2; ++mi) {
#pragma unroll
                for (int r = 0; r < 16; ++r) {
                    const int row = mi * 32 + (r & 3) + 4 * khalf + 8 * (r >> 2);
                    float v = fmaxf(acc[mi][ni][r] + bb[ni], 0.f);
                    H[cbase + (row ^ fw) * 8 + j] = (f16)v;
                    acc[mi][ni][r] = 0.f;
                }
            }
        }
        __syncthreads();                    // H rewrite complete
    };

    run_layer(T2);
    writeback(gb2);
    run_layer(T3);
    writeback(gb3);
    run_layer(T4);

    // ---- layer-4 epilogue: relu(acc+b4), col-sum over the block's 64 rows ----
#pragma unroll
    for (int ni = 0; ni < 2; ++ni) {
        const int col = wv * 64 + ni * 32 + lane31;
        float bb = gb4[col];
        float s = 0.f;
#pragma unroll
        for (int mi = 0; mi < 2; ++mi)
#pragma unroll
            for (int r = 0; r < 16; ++r)
                s += fmaxf(acc[mi][ni][r] + bb, 0.f);
        s += __shfl_xor(s, 32, 64);         // combine the two khalf lanes
        if (khalf == 0)
            atomicAdd(&Ctx[(((size_t)nb) << 9) + col], s);
    }
}

// ---------------------------------------------------------------------------
// f-MLP layer: Out[n, cs*64..+64) = relu(In[n,:]*scale @ W + b).
// ---------------------------------------------------------------------------
__global__ __launch_bounds__(512) void fmlp_layer(
    const float* __restrict__ In, const float* __restrict__ Wt,
    const float* __restrict__ bias, float* __restrict__ Out, float scale) {
    const int n = blockIdx.x, cs = blockIdx.y;
    const int t = threadIdx.x;
    const int col = cs * 64 + (t & 63);
    const int seg = t >> 6;
    __shared__ float a[512];
    __shared__ float red[512];
    a[t] = In[(size_t)n * 512 + t] * scale;
    __syncthreads();
    float p = 0.f;
#pragma unroll 8
    for (int i = seg * 64; i < seg * 64 + 64; ++i)
        p += a[i] * Wt[(size_t)i * 512 + col];
    red[t] = p;
    __syncthreads();
    if (t < 64) {
        float v = bias[col];
#pragma unroll
        for (int sg = 0; sg < 8; ++sg) v += red[sg * 64 + t];
        Out[(size_t)n * 512 + cs * 64 + t] = fmaxf(v, 0.f);
    }
}

// ---------------------------------------------------------------------------
// Final logits + log_softmax. grid 64, block 64 (one wave per batch row).
// ---------------------------------------------------------------------------
__global__ __launch_bounds__(64) void fmlp_out(
    const float* __restrict__ A2, const float* __restrict__ fw3,
    const float* __restrict__ fb3, float* __restrict__ out) {
    const int n = blockIdx.x;
    const int lane = threadIdx.x;
    float s0 = 0.f, s1 = 0.f;
    for (int i = lane; i < 512; i += 64) {
        float v = A2[(size_t)n * 512 + i];
        s0 += v * fw3[i * 2];
        s1 += v * fw3[i * 2 + 1];
    }
#pragma unroll
    for (int d = 1; d < 64; d <<= 1) {
        s0 += __shfl_xor(s0, d, 64);
        s1 += __shfl_xor(s1, d, 64);
    }
    if (lane == 0) {
        s0 += fb3[0];
        s1 += fb3[1];
        float m = fmaxf(s0, s1);
        float l = logf(expf(s0 - m) + expf(s1 - m)) + m;
        out[n * 2 + 0] = s0 - l;
        out[n * 2 + 1] = s1 - l;
    }
}

// ---------------------------------------------------------------------------
extern "C" void kernel_launch(void* const* d_in, const int* in_sizes, int n_in,
                              void* d_out, int out_size, void* d_ws, size_t ws_size,
                              hipStream_t stream) {
    const float* img  = (const float*)d_in[0];
    const float* ques = (const float*)d_in[1];
    const float* gw1  = (const float*)d_in[2];
    const float* gb1  = (const float*)d_in[3];
    const float* gw2  = (const float*)d_in[4];
    const float* gb2  = (const float*)d_in[5];
    const float* gw3  = (const float*)d_in[6];
    const float* gb3  = (const float*)d_in[7];
    const float* gw4  = (const float*)d_in[8];
    const float* gb4  = (const float*)d_in[9];
    const float* fw1  = (const float*)d_in[10];
    const float* fb1  = (const float*)d_in[11];
    const float* fw2  = (const float*)d_in[12];
    const float* fb2  = (const float*)d_in[13];
    const float* fw3  = (const float*)d_in[14];
    const float* fb3  = (const float*)d_in[15];

    char* ws = (char*)d_ws;
    size_t off = 0;
    float* P1  = (float*)(ws + off); off += (size_t)4096 * 512 * 4;   // 8 MB fp32 scratch
    f16* P1c = (f16*)(ws + off); off += (size_t)4096 * 512 * 2;       // 4 MB chunk-major
    f16* P2c = (f16*)(ws + off); off += (size_t)4096 * 512 * 2;       // 4 MB chunk-major
    float* Ctx = (float*)(ws + off); off += (size_t)64 * 512 * 4;
    float* Z1  = (float*)(ws + off); off += (size_t)64 * 512 * 4;
    float* Z2  = (float*)(ws + off); off += (size_t)64 * 512 * 4;
    f16* T2 = (f16*)(ws + off); off += (size_t)512 * 512 * 2;
    f16* T3 = (f16*)(ws + off); off += (size_t)512 * 512 * 2;
    f16* T4 = (f16*)(ws + off); off += (size_t)512 * 512 * 2;

    prep_p12<<<512, 512, 0, stream>>>(img, gw1, P1, P2c);
    prep_q2<<<64, 512, 0, stream>>>(ques, gw1, gb1, P1, P1c, Ctx);
    transpose_w<<<dim3(16, 16, 3), dim3(32, 8), 0, stream>>>(gw2, gw3, gw4, T2, T3, T4);

    // one fused dispatch; 64-row blocks, 2 co-resident per CU
    fused_g234<<<4096, 512, 0, stream>>>(P1c, P2c, T2, T3, T4, gb2, gb3, gb4, Ctx);

    fmlp_layer<<<dim3(64, 8), 512, 0, stream>>>(Ctx, fw1, fb1, Z1, 1.0f / 4096.0f);
    fmlp_layer<<<dim3(64, 8), 512, 0, stream>>>(Z1, fw2, fb2, Z2, 1.0f);
    fmlp_out<<<64, 64, 0, stream>>>(Z2, fw3, fb3, (float*)d_out);
}

// Round 11
// 491.231 us; speedup vs baseline: 1.1474x; 1.1071x over previous
//
#include <hip/hip_runtime.h>

typedef unsigned short u16;
typedef unsigned int u32;
typedef _Float16 f16;

using half8 = __attribute__((ext_vector_type(8))) _Float16;
using f32x4 = __attribute__((ext_vector_type(4))) float;
using f32x16 = __attribute__((ext_vector_type(16))) float;

// Chunk-major activation layout (MFMA-fragment-native), per image n:
//   idx(n,k,cell) = n*32768 + (k>>4)*1024 + ((k>>3)&1)*512 + cell*8 + (k&7)
// i.e. [ks:32][khalf:2][cell:64][j:8]. A wave reading all 64 cells' 16B
// fragments at fixed (ks,khalf) touches contiguous memory.

// ---------------------------------------------------------------------------
// Prep 1: P1 = feats @ W1a (fp32 row-major, Qc folded later),
//         P2c = f16(feats @ W1b) in chunk-major layout.
// ---------------------------------------------------------------------------
__global__ __launch_bounds__(512) void prep_p12(const float* __restrict__ img,
                                                const float* __restrict__ gw1,
                                                float* __restrict__ P1,
                                                f16* __restrict__ P2c) {
    const int blk = blockIdx.x;
    const int n = blk >> 3;
    const int c0 = (blk & 7) * 8;
    const int t = threadIdx.x;
    __shared__ float feats[8][68];
    for (int idx = t; idx < 8 * 66; idx += 512) {
        int rr = idx / 66, cc = idx % 66, cell = c0 + rr;
        float v;
        if (cc < 64)       v = img[((size_t)(n * 64 + cc)) * 64 + cell];
        else if (cc == 64) v = (float)(cell >> 3);
        else               v = (float)(cell & 7);
        feats[rr][cc] = v;
    }
    __syncthreads();
    const int g = t;
    float a1[8], a2[8];
#pragma unroll
    for (int r = 0; r < 8; ++r) { a1[r] = 0.f; a2[r] = 0.f; }
    for (int c = 0; c < 66; ++c) {
        float wa = gw1[(size_t)c * 512 + g];
        float wb = gw1[(size_t)(66 + c) * 512 + g];
#pragma unroll
        for (int r = 0; r < 8; ++r) {
            a1[r] += feats[r][c] * wa;
            a2[r] += feats[r][c] * wb;
        }
    }
    const size_t cb = (size_t)n * 32768 + (g >> 4) * 1024 + ((g >> 3) & 1) * 512 + (g & 7);
#pragma unroll
    for (int r = 0; r < 8; ++r) {
        P1[((size_t)(n * 64 + c0 + r)) * 512 + g] = a1[r];
        P2c[cb + (c0 + r) * 8] = (f16)a2[r];
    }
}

// ---------------------------------------------------------------------------
// Prep 2: Qc[n] = ques[n] @ W1c + b1; P1c = f16(P1 + Qc) chunk-major. Zero Ctx.
// ---------------------------------------------------------------------------
__global__ __launch_bounds__(512) void prep_q2(const float* __restrict__ ques,
                                               const float* __restrict__ gw1,
                                               const float* __restrict__ gb1,
                                               const float* __restrict__ P1,
                                               f16* __restrict__ P1c,
                                               float* __restrict__ Ctx) {
    const int n = blockIdx.x;
    const int t = threadIdx.x;
    __shared__ float q[256];
    if (t < 256) q[t] = ques[(size_t)n * 256 + t];
    __syncthreads();
    float acc = gb1[t];
    for (int e = 0; e < 256; ++e)
        acc += q[e] * gw1[(size_t)(132 + e) * 512 + t];
    const float* src = P1 + (((size_t)(n * 64)) << 9) + t;
    const size_t cb = (size_t)n * 32768 + (t >> 4) * 1024 + ((t >> 3) & 1) * 512 + (t & 7);
    for (int r = 0; r < 64; ++r)
        P1c[cb + r * 8] = (f16)(src[(size_t)r * 512] + acc);
    Ctx[(size_t)n * 512 + t] = 0.f;
}

// ---------------------------------------------------------------------------
// Prep 3: reorder W2/W3/W4 (512x512 fp32 [k][n]) into K-chunk-major f16:
//   T'[ks][khalf][col][8]: halfidx = ks*8192 + khalf*4096 + col*8 + (k&7)
// (16 KB per ks chunk; per-wave B-fragment loads are contiguous 512 B.)
// ---------------------------------------------------------------------------
__global__ void transpose_w(const float* __restrict__ W2, const float* __restrict__ W3,
                            const float* __restrict__ W4, f16* __restrict__ T2,
                            f16* __restrict__ T3, f16* __restrict__ T4) {
    const int L = blockIdx.z;
    const float* W = (L == 0) ? W2 : ((L == 1) ? W3 : W4);
    f16* T = (L == 0) ? T2 : ((L == 1) ? T3 : T4);
    __shared__ float tile[32][33];
    const int bx = blockIdx.x * 32;  // n origin
    const int by = blockIdx.y * 32;  // k origin
    const int tx = threadIdx.x, ty = threadIdx.y;
    for (int r = ty; r < 32; r += 8)
        tile[r][tx] = W[(size_t)(by + r) * 512 + bx + tx];
    __syncthreads();
    for (int r = ty; r < 32; r += 8) {
        const int n = bx + r, k = by + tx;
        T[(size_t)(k >> 4) * 8192 + ((k >> 3) & 1) * 4096 + n * 8 + (k & 7)] =
            (f16)tile[tx][r];
    }
}

// ---------------------------------------------------------------------------
// FUSED g-MLP layers 2..4 + mean-reduce. 32x32x16 MFMA, 1x8 N-split,
// H = 64 rows (one i-index/block), 64 KB LDS, (512,4) -> 2 blocks/CU.
// Round-10 post-mortem: occupancy doubled (42%) and conflicts stayed 0, but
// the (512,4) cap (64 arch + 64 acc) forced ~14 regs into scratch:
// WRITE_SIZE 112 MB = 56 B/thread spill traffic inside the K-loop; the
// occupancy gain and the spill cost cancelled (463 -> 426 us only).
// Natural arch demand was 88 (r9); the ~24-reg excess is exactly the K-loop
// redundancy. REGISTER DIET, same structure:
//  - two named B-sets (bA/bB) alternating even/odd phases: kills the bf
//    copy (8 regs + 8 movs/iter), keeps depth-1 prefetch (r6-proven flow).
//  - lean addressing: one 32-bit B byte-offset walking +16384/ks against
//    the SGPR T base; two precomputed A offsets (even/odd XOR phase);
//    #pragma unroll 1 bounds live ranges (no load hoisting).
// Estimated arch live ~50 <= 64 -> no spill at 2 blocks/CU.
// Fragment layouts (guide m74/m101):
//   A/B: row|col = lane&31, k = (lane>>5)*8 + j
//   C/D: col = lane&31, row = (reg&3) + 8*(reg>>2) + 4*(lane>>5)
// ---------------------------------------------------------------------------
__global__ __launch_bounds__(512, 4) void fused_g234(
    const f16* __restrict__ P1c, const f16* __restrict__ P2c,
    const f16* __restrict__ T2, const f16* __restrict__ T3,
    const f16* __restrict__ T4, const float* __restrict__ gb2,
    const float* __restrict__ gb3, const float* __restrict__ gb4,
    float* __restrict__ Ctx) {
    const int tid = threadIdx.x;
    const int lane = tid & 63;
    const int lane31 = lane & 31;
    const int khalf = lane >> 5;        // 0..1 (k-subgroup of 8 within ks*16)
    const int wv = tid >> 6;            // 0..7 (column group of 64)
    const int b = blockIdx.x;
    const int nb = b >> 6;              // image 0..63
    const int i0 = b & 63;              // the single i-index of this block

    __shared__ alignas(16) f16 H[32 * 1024];   // 64 KB exactly -> 2 blocks/CU

    const f16* P1b = P1c + (size_t)nb * 32768;
    const f16* P2b = P2c + (size_t)nb * 32768;

    // ---- construct: H[r][k] = relu(P1[i0][k] + P2[r][k]), chunk-major ----
    // wave wv owns ks = wv*4+u. Per iter: coalesced 512B reads, 1KB LDS write.
#pragma unroll
    for (int u = 0; u < 4; ++u) {
        const int ks = wv * 4 + u;
        const int cb = ks * 1024 + khalf * 512;
        const int f = ((ks & 1) << 1) | khalf;
        half8 x = *(const half8*)(P1b + cb + i0 * 8);
#pragma unroll
        for (int rr = 0; rr < 2; ++rr) {
            half8 y = *(const half8*)(P2b + cb + (rr * 32 + lane31) * 8);
            half8 s = x + y;
            s = __builtin_elementwise_max(s, (half8)(f16)0.f);
            *(half8*)&H[cb + (rr * 32 + (lane31 ^ f)) * 8] = s;
        }
    }
    __syncthreads();

    f32x16 acc[2][2];
#pragma unroll
    for (int mi = 0; mi < 2; ++mi)
#pragma unroll
        for (int ni = 0; ni < 2; ++ni)
#pragma unroll
            for (int r = 0; r < 16; ++r)
                acc[mi][ni][r] = 0.f;

    // Per-lane invariant offsets.
    //   A (halves): even ks -> f = khalf; odd ks -> f = 2|khalf.
    const int aoffE = khalf * 512 + (lane31 ^ khalf) * 8;
    const int aoffO = khalf * 512 + (lane31 ^ (2 | khalf)) * 8;
    //   B (bytes): against the SGPR-held T base; walks +16384 per ks.
    const u32 boff = (u32)(khalf * 4096 + (wv * 64 + lane31) * 8) * 2u;

    auto mfma4 = [&](half8 a0, half8 a1, half8 b0, half8 b1) {
        __builtin_amdgcn_s_setprio(1);
        acc[0][0] = __builtin_amdgcn_mfma_f32_32x32x16_f16(a0, b0, acc[0][0], 0, 0, 0);
        acc[0][1] = __builtin_amdgcn_mfma_f32_32x32x16_f16(a0, b1, acc[0][1], 0, 0, 0);
        acc[1][0] = __builtin_amdgcn_mfma_f32_32x32x16_f16(a1, b0, acc[1][0], 0, 0, 0);
        acc[1][1] = __builtin_amdgcn_mfma_f32_32x32x16_f16(a1, b1, acc[1][1], 0, 0, 0);
        __builtin_amdgcn_s_setprio(0);
    };

    // One 512-K layer: 32 ks chunks as 16 even/odd pairs. Named B-sets
    // alternate (no copy); A read in-iteration from LDS (imm-offset pair).
    auto run_layer = [&](const f16* __restrict__ T) {
        const char* Tb = (const char*)T;
        u32 vo = boff;
        half8 bA0 = *(const half8*)(Tb + vo);
        half8 bA1 = *(const half8*)(Tb + vo + 512);
        half8 bB0, bB1;
#pragma unroll 1
        for (int k2 = 0; k2 < 16; ++k2) {
            const int e0 = aoffE + k2 * 2048;      // even-phase A offset (halves)
            vo += 16384;
            bB0 = *(const half8*)(Tb + vo);        // prefetch odd ks
            bB1 = *(const half8*)(Tb + vo + 512);
            {
                half8 a0 = *(const half8*)&H[e0];
                half8 a1 = *(const half8*)&H[e0 + 256];
                mfma4(a0, a1, bA0, bA1);
            }
            if (k2 < 15) {
                vo += 16384;
                bA0 = *(const half8*)(Tb + vo);    // prefetch next even ks
                bA1 = *(const half8*)(Tb + vo + 512);
            }
            {
                const int o0 = aoffO + k2 * 2048 + 1024;   // odd-phase A offset
                half8 a0 = *(const half8*)&H[o0];
                half8 a1 = *(const half8*)&H[o0 + 256];
                mfma4(a0, a1, bB0, bB1);
            }
        }
    };

    // relu(acc+bias) -> f16 -> H chunk-major (slot XOR). Two barriers.
    auto writeback = [&](const float* __restrict__ bias) {
        float bb[2];
#pragma unroll
        for (int ni = 0; ni < 2; ++ni)
            bb[ni] = bias[wv * 64 + ni * 32 + lane31];
        __syncthreads();                    // all waves done reading H
#pragma unroll
        for (int ni = 0; ni < 2; ++ni) {
            const int c = wv * 64 + ni * 32 + lane31;
            const int cbase = (c >> 4) * 1024 + ((c >> 3) & 1) * 512;
            const int fw = (((c >> 4) & 1) << 1) | ((c >> 3) & 1);
            const int j = c & 7;
#pragma unroll
            for (int mi = 0; mi < 2; ++mi) {
#pragma unroll
                for (int r = 0; r < 16; ++r) {
                    const int row = mi * 32 + (r & 3) + 4 * khalf + 8 * (r >> 2);
                    float v = fmaxf(acc[mi][ni][r] + bb[ni], 0.f);
                    H[cbase + (row ^ fw) * 8 + j] = (f16)v;
                    acc[mi][ni][r] = 0.f;
                }
            }
        }
        __syncthreads();                    // H rewrite complete
    };

    run_layer(T2);
    writeback(gb2);
    run_layer(T3);
    writeback(gb3);
    run_layer(T4);

    // ---- layer-4 epilogue: relu(acc+b4), col-sum over the block's 64 rows ----
#pragma unroll
    for (int ni = 0; ni < 2; ++ni) {
        const int col = wv * 64 + ni * 32 + lane31;
        float bb = gb4[col];
        float s = 0.f;
#pragma unroll
        for (int mi = 0; mi < 2; ++mi)
#pragma unroll
            for (int r = 0; r < 16; ++r)
                s += fmaxf(acc[mi][ni][r] + bb, 0.f);
        s += __shfl_xor(s, 32, 64);         // combine the two khalf lanes
        if (khalf == 0)
            atomicAdd(&Ctx[(((size_t)nb) << 9) + col], s);
    }
}

// ---------------------------------------------------------------------------
// f-MLP layer: Out[n, cs*64..+64) = relu(In[n,:]*scale @ W + b).
// ---------------------------------------------------------------------------
__global__ __launch_bounds__(512) void fmlp_layer(
    const float* __restrict__ In, const float* __restrict__ Wt,
    const float* __restrict__ bias, float* __restrict__ Out, float scale) {
    const int n = blockIdx.x, cs = blockIdx.y;
    const int t = threadIdx.x;
    const int col = cs * 64 + (t & 63);
    const int seg = t >> 6;
    __shared__ float a[512];
    __shared__ float red[512];
    a[t] = In[(size_t)n * 512 + t] * scale;
    __syncthreads();
    float p = 0.f;
#pragma unroll 8
    for (int i = seg * 64; i < seg * 64 + 64; ++i)
        p += a[i] * Wt[(size_t)i * 512 + col];
    red[t] = p;
    __syncthreads();
    if (t < 64) {
        float v = bias[col];
#pragma unroll
        for (int sg = 0; sg < 8; ++sg) v += red[sg * 64 + t];
        Out[(size_t)n * 512 + cs * 64 + t] = fmaxf(v, 0.f);
    }
}

// ---------------------------------------------------------------------------
// Final logits + log_softmax. grid 64, block 64 (one wave per batch row).
// ---------------------------------------------------------------------------
__global__ __launch_bounds__(64) void fmlp_out(
    const float* __restrict__ A2, const float* __restrict__ fw3,
    const float* __restrict__ fb3, float* __restrict__ out) {
    const int n = blockIdx.x;
    const int lane = threadIdx.x;
    float s0 = 0.f, s1 = 0.f;
    for (int i = lane; i < 512; i += 64) {
        float v = A2[(size_t)n * 512 + i];
        s0 += v * fw3[i * 2];
        s1 += v * fw3[i * 2 + 1];
    }
#pragma unroll
    for (int d = 1; d < 64; d <<= 1) {
        s0 += __shfl_xor(s0, d, 64);
        s1 += __shfl_xor(s1, d, 64);
    }
    if (lane == 0) {
        s0 += fb3[0];
        s1 += fb3[1];
        float m = fmaxf(s0, s1);
        float l = logf(expf(s0 - m) + expf(s1 - m)) + m;
        out[n * 2 + 0] = s0 - l;
        out[n * 2 + 1] = s1 - l;
    }
}

// ---------------------------------------------------------------------------
extern "C" void kernel_launch(void* const* d_in, const int* in_sizes, int n_in,
                              void* d_out, int out_size, void* d_ws, size_t ws_size,
                              hipStream_t stream) {
    const float* img  = (const float*)d_in[0];
    const float* ques = (const float*)d_in[1];
    const float* gw1  = (const float*)d_in[2];
    const float* gb1  = (const float*)d_in[3];
    const float* gw2  = (const float*)d_in[4];
    const float* gb2  = (const float*)d_in[5];
    const float* gw3  = (const float*)d_in[6];
    const float* gb3  = (const float*)d_in[7];
    const float* gw4  = (const float*)d_in[8];
    const float* gb4  = (const float*)d_in[9];
    const float* fw1  = (const float*)d_in[10];
    const float* fb1  = (const float*)d_in[11];
    const float* fw2  = (const float*)d_in[12];
    const float* fb2  = (const float*)d_in[13];
    const float* fw3  = (const float*)d_in[14];
    const float* fb3  = (const float*)d_in[15];

    char* ws = (char*)d_ws;
    size_t off = 0;
    float* P1  = (float*)(ws + off); off += (size_t)4096 * 512 * 4;   // 8 MB fp32 scratch
    f16* P1c = (f16*)(ws + off); off += (size_t)4096 * 512 * 2;       // 4 MB chunk-major
    f16* P2c = (f16*)(ws + off); off += (size_t)4096 * 512 * 2;       // 4 MB chunk-major
    float* Ctx = (float*)(ws + off); off += (size_t)64 * 512 * 4;
    float* Z1  = (float*)(ws + off); off += (size_t)64 * 512 * 4;
    float* Z2  = (float*)(ws + off); off += (size_t)64 * 512 * 4;
    f16* T2 = (f16*)(ws + off); off += (size_t)512 * 512 * 2;
    f16* T3 = (f16*)(ws + off); off += (size_t)512 * 512 * 2;
    f16* T4 = (f16*)(ws + off); off += (size_t)512 * 512 * 2;

    prep_p12<<<512, 512, 0, stream>>>(img, gw1, P1, P2c);
    prep_q2<<<64, 512, 0, stream>>>(ques, gw1, gb1, P1, P1c, Ctx);
    transpose_w<<<dim3(16, 16, 3), dim3(32, 8), 0, stream>>>(gw2, gw3, gw4, T2, T3, T4);

    // one fused dispatch; 64-row blocks, 2 co-resident per CU
    fused_g234<<<4096, 512, 0, stream>>>(P1c, P2c, T2, T3, T4, gb2, gb3, gb4, Ctx);

    fmlp_layer<<<dim3(64, 8), 512, 0, stream>>>(Ctx, fw1, fb1, Z1, 1.0f / 4096.0f);
    fmlp_layer<<<dim3(64, 8), 512, 0, stream>>>(Z1, fw2, fb2, Z2, 1.0f);
    fmlp_out<<<64, 64, 0, stream>>>(Z2, fw3, fb3, (float*)d_out);
}